// Round 16
// baseline (863.016 us; speedup 1.0000x reference)
//
#include <hip/hip_runtime.h>
#include <hip/hip_bf16.h>

typedef float f32x4 __attribute__((ext_vector_type(4)));
typedef short s16x8 __attribute__((ext_vector_type(8)));

#define MFMA16(A,B,C) __builtin_amdgcn_mfma_f32_16x16x32_bf16((A),(B),(C),0,0,0)

// Hardware RNE f32->bf16 (v_cvt_pk_bf16_f32 when paired).
__device__ __forceinline__ short f2bf(float f) {
  return (short)__bfloat16_as_ushort(__float2bfloat16(f));
}

__device__ __forceinline__ void gload_lds16(const void* g, void* l) {
  __builtin_amdgcn_global_load_lds(
      (const __attribute__((address_space(1))) unsigned*)g,
      (__attribute__((address_space(3))) unsigned*)l, 16, 0, 0);
}

// ---------------- prep: transpose weights to bf16[N][K], gather bias table ----
__global__ __launch_bounds__(256) void prep_kernel(
    const float* __restrict__ Wqkv, const float* __restrict__ Wo,
    const float* __restrict__ posb, const int* __restrict__ relp,
    short* __restrict__ WqkvT, short* __restrict__ WoT, float* __restrict__ biasF)
{
  int i = blockIdx.x * 256 + threadIdx.x;
  if (i < 1152 * 384) {
    int n = i / 384, k = i % 384;
    WqkvT[i] = f2bf(Wqkv[k * 1152 + n]);
  } else if (i < 1152 * 384 + 384 * 384) {
    int j = i - 1152 * 384;
    int n = j / 384, k = j % 384;
    WoT[j] = f2bf(Wo[k * 384 + n]);
  } else {
    int j = i - (1152 * 384 + 384 * 384);    // j < 12*64*64 = 49152
    int h = j >> 12, qk = j & 4095;
    biasF[j] = posb[h * 16129 + relp[qk]];
  }
}

// ---------------- X f32 -> bf16 (memory-bound, vectorized) --------------------
__global__ __launch_bounds__(256) void xcvt_kernel(
    const float* __restrict__ X, short* __restrict__ Xbf)
{
  const int n8 = 4816896;                  // 38,535,168 / 8
  for (int i = blockIdx.x * 256 + threadIdx.x; i < n8; i += gridDim.x * 256) {
    float4 a = *(const float4*)(X + (size_t)i * 8);
    float4 b = *(const float4*)(X + (size_t)i * 8 + 4);
    s16x8 p;
    p[0] = f2bf(a.x); p[1] = f2bf(a.y); p[2] = f2bf(a.z); p[3] = f2bf(a.w);
    p[4] = f2bf(b.x); p[5] = f2bf(b.y); p[6] = f2bf(b.z); p[7] = f2bf(b.w);
    *(s16x8*)(Xbf + (size_t)i * 8) = p;
  }
}

// ---------------- fused QKV GEMM + attention (2 heads / block) ----------------
// R15 structure with the B operand moved OUT of LDS: W fragments are read
// per-lane straight from L2-hot WqkvT (884 KB) inside COMPUTE. This deletes
// the 48KB B double-buffer (LDS 80->39KB => 4 blocks/CU, 2x TLP) and all B
// staging/ds_reads. STAGE = 4 A gload_lds only -> counted vmcnt(4) (tail 0);
// compiler manages waits for its own B loads. Swapped-operand GEMM (W·X^T),
// in-register Q/K, attn path unchanged from R15 (HW-verified).
__global__ __launch_bounds__(256, 4) void qkv_attn(
    const short* __restrict__ Xbf, const short* __restrict__ WqkvT,
    const float* __restrict__ biasF, short* __restrict__ AO)
{
  __shared__ short lds[19968];   // A dbuf: sel*8192 (32KB); attn scratch reuses
  const int bid = blockIdx.x;
  const int wg = (bid & 7) * 588 + (bid >> 3);   // XCD swizzle (4704 = 8*588)
  const int hg = wg % 6, mt = wg / 6;
  const int t = threadIdx.x;
  const int wv = t >> 6, l = t & 63, lr = l & 15, lg = l >> 4;
  const int wm = wv >> 1, wn = wv & 1;

  f32x4 acc[6][4];               // [fn: q0,q1,k0,k1,v0,v1][fm: token block]
#pragma unroll
  for (int fn = 0; fn < 6; ++fn)
#pragma unroll
    for (int fm = 0; fm < 4; ++fm) acc[fn][fm] = (f32x4)0.0f;

  const int cgs = (l & 7) ^ (l >> 3);
  const short* AbT = Xbf + (size_t)(mt * 128 + wv * 32 + (l >> 3)) * 384 + cgs * 8;
  // per-lane B fragment bases: row = (fn>>1)*384 + hg*64 + wn*32 + (fn&1)*16+lr
  const short* Bb[6];
#pragma unroll
  for (int fn = 0; fn < 6; ++fn)
    Bb[fn] = WqkvT + (size_t)((fn >> 1) * 384 + hg * 64 + wn * 32
                              + (fn & 1) * 16 + lr) * 384 + lg * 8;

#define STAGE(KS, SEL) do {                                                  \
  _Pragma("unroll")                                                          \
  for (int i_ = 0; i_ < 4; ++i_)                                             \
    gload_lds16(AbT + i_ * 3072 + (KS) * 64,                                 \
                lds + (SEL) * 8192 + (wv * 4 + i_) * 512);                   \
  } while (0)

#define COMPUTE(T) do {                                                      \
  const short* Acur_ = lds + ((T) & 1) * 8192;                               \
  _Pragma("unroll")                                                          \
  for (int kk = 0; kk < 2; ++kk) {                                           \
    s16x8 af[4], bq[6];                                                      \
    _Pragma("unroll")                                                        \
    for (int fn = 0; fn < 6; ++fn)                                           \
      bq[fn] = *(const s16x8*)(Bb[fn] + (T) * 64 + kk * 32);                 \
    _Pragma("unroll")                                                        \
    for (int f = 0; f < 4; ++f) {                                            \
      const int arow = wm * 64 + f * 16 + lr;                                \
      const int ac = (kk * 4 + lg) ^ (arow & 7);                             \
      af[f] = *(const s16x8*)(Acur_ + arow * 64 + ac * 8);                   \
    }                                                                        \
    _Pragma("unroll")                                                        \
    for (int fn = 0; fn < 6; ++fn)                                           \
      _Pragma("unroll")                                                      \
      for (int fm = 0; fm < 4; ++fm)                                         \
        acc[fn][fm] = MFMA16(bq[fn], af[fm], acc[fn][fm]);   /* W·X^T */     \
  } } while (0)

#define ITER(T, WN) do {                                                     \
  asm volatile("s_waitcnt vmcnt(" #WN ")" ::: "memory");                     \
  __builtin_amdgcn_s_barrier();                                              \
  COMPUTE(T);                                                                \
  asm volatile("s_waitcnt lgkmcnt(0)" ::: "memory");  /* WAR drain */        \
  __builtin_amdgcn_s_barrier();                                              \
  if ((T) + 2 < 6) STAGE((T) + 2, (T) & 1);                                  \
  } while (0)

  STAGE(0, 0);
  STAGE(1, 1);
  ITER(0, 4); ITER(1, 4); ITER(2, 4); ITER(3, 4); ITER(4, 4); ITER(5, 0);
#undef ITER
#undef COMPUTE
#undef STAGE

  // final ITER's lgkm(0)+barrier drained all GEMM LDS reads block-wide;
  // per-wave attn scratch below may overwrite the A dbuf region.

  // ---- attention, one (window, head) per wave; Q/K stay in registers ----
  const int w = mt * 2 + wm, h = hg * 2 + wn;
  short* Vts = lds + wv * 4992;          // [32][76] V^T (stride 76: no 4-way)
  short* Os  = Vts + 2432;               // [64][40] epilogue staging

  // V scatter: Vts[d][tok], d = fv*16+lg*4+r, tok = fm*16+lr
#pragma unroll
  for (int fv = 0; fv < 2; ++fv)
#pragma unroll
    for (int fm = 0; fm < 4; ++fm)
#pragma unroll
      for (int r = 0; r < 4; ++r)
        Vts[(fv * 16 + lg * 4 + r) * 76 + fm * 16 + lr] =
            f2bf(acc[4 + fv][fm][r]);

  // pack K (A-op: lane=row kt) and Q (B-op: lane=col q) frags in-register;
  // slot j -> d = 16*(j>>2) + 4*lg + (j&3)  (same sigma on both operands)
  s16x8 ka[4], qb[4];
#pragma unroll
  for (int f = 0; f < 4; ++f) {
    s16x8 tk, tq;
#pragma unroll
    for (int j = 0; j < 8; ++j) {
      tk[j] = f2bf(acc[2 + (j >> 2)][f][j & 3]);
      tq[j] = f2bf(acc[0 + (j >> 2)][f][j & 3]);
    }
    ka[f] = tk; qb[f] = tq;
  }

  // S^T = K·Q^T  (rows kt, cols q), K-dim 32
  f32x4 st[4][4];
#pragma unroll
  for (int fk = 0; fk < 4; ++fk)
#pragma unroll
    for (int fq = 0; fq < 4; ++fq)
      st[fk][fq] = MFMA16(ka[fk], qb[fq], (f32x4)0.0f);

  // scale + bias + softmax over kt (per q column, per-lane + shfl 16/32)
  const float* bh = biasF + h * 4096;
#pragma unroll
  for (int fq = 0; fq < 4; ++fq) {
    const int q = fq * 16 + lr;
    float4 bv[4];
#pragma unroll
    for (int fk = 0; fk < 4; ++fk)
      bv[fk] = *(const float4*)(bh + q * 64 + fk * 16 + lg * 4);
    float mx = -3.0e38f;
#pragma unroll
    for (int fk = 0; fk < 4; ++fk)
#pragma unroll
      for (int r = 0; r < 4; ++r) {
        float v = st[fk][fq][r] * 0.17677669529663687f + ((const float*)&bv[fk])[r];
        st[fk][fq][r] = v;
        mx = fmaxf(mx, v);
      }
    mx = fmaxf(mx, __shfl_xor(mx, 16));
    mx = fmaxf(mx, __shfl_xor(mx, 32));
    float sm = 0.0f;
#pragma unroll
    for (int fk = 0; fk < 4; ++fk)
#pragma unroll
      for (int r = 0; r < 4; ++r) {
        float e = __expf(st[fk][fq][r] - mx);
        st[fk][fq][r] = e;
        sm += e;
      }
    sm += __shfl_xor(sm, 16);
    sm += __shfl_xor(sm, 32);
    const float inv = 1.0f / sm;
#pragma unroll
    for (int fk = 0; fk < 4; ++fk)
#pragma unroll
      for (int r = 0; r < 4; ++r) st[fk][fq][r] *= inv;
  }

  // O^T = V^T · P^T ; sigma(g,j)=32kb+16(j>>2)+4g+(j&3) on both operands
  s16x8 va[2][2];
#pragma unroll
  for (int fd = 0; fd < 2; ++fd)
#pragma unroll
    for (int kb = 0; kb < 2; ++kb) {
      short4 v0 = *(const short4*)(Vts + (fd * 16 + lr) * 76 + kb * 32 + lg * 4);
      short4 v1 = *(const short4*)(Vts + (fd * 16 + lr) * 76 + kb * 32 + 16 + lg * 4);
      s16x8 tv;
      tv[0] = v0.x; tv[1] = v0.y; tv[2] = v0.z; tv[3] = v0.w;
      tv[4] = v1.x; tv[5] = v1.y; tv[6] = v1.z; tv[7] = v1.w;
      va[fd][kb] = tv;
    }
  f32x4 ot[2][4];
#pragma unroll
  for (int fd = 0; fd < 2; ++fd)
#pragma unroll
    for (int fq = 0; fq < 4; ++fq) ot[fd][fq] = (f32x4)0.0f;
#pragma unroll
  for (int kb = 0; kb < 2; ++kb)
#pragma unroll
    for (int fq = 0; fq < 4; ++fq) {
      s16x8 pb;
#pragma unroll
      for (int j = 0; j < 8; ++j)
        pb[j] = f2bf(st[2 * kb + (j >> 2)][fq][j & 3]);   // lane-local repack
#pragma unroll
      for (int fd = 0; fd < 2; ++fd)
        ot[fd][fq] = MFMA16(va[fd][kb], pb, ot[fd][fq]);
    }

  // epilogue: stage O [q][d] in Os, write coalesced 64B rows
#pragma unroll
  for (int fd = 0; fd < 2; ++fd)
#pragma unroll
    for (int fq = 0; fq < 4; ++fq)
#pragma unroll
      for (int r = 0; r < 4; ++r)
        Os[(fq * 16 + lr) * 40 + fd * 16 + lg * 4 + r] = f2bf(ot[fd][fq][r]);
  short* dst = AO + ((size_t)w * 64 + l) * 384 + h * 32;
  int4 o0 = *(const int4*)(Os + l * 40);
  int4 o1 = *(const int4*)(Os + l * 40 + 8);
  int4 o2 = *(const int4*)(Os + l * 40 + 16);
  int4 o3 = *(const int4*)(Os + l * 40 + 24);
  *(int4*)(dst)      = o0;
  *(int4*)(dst + 8)  = o1;
  *(int4*)(dst + 16) = o2;
  *(int4*)(dst + 24) = o3;
}

// ---------------- output projection: out = AO(bf16) @ Wo + bo, f32 out --------
// R7-proven BK=64 2-deep counted-vmcnt pipeline.
__global__ __launch_bounds__(256) void proj_kernel(
    const short* __restrict__ AO, const short* __restrict__ WoT,
    const float* __restrict__ bo, float* __restrict__ out)
{
  __shared__ short lds[32768];
  const int bid = blockIdx.x;
  const int wg = (bid & 7) * 294 + (bid >> 3);   // XCD swizzle (2352 = 8*294)
  const int nt = wg % 3, mt = wg / 3;
  const int t = threadIdx.x;
  const int wv = t >> 6, l = t & 63, lr = l & 15, lg = l >> 4;
  const int wm = wv >> 1, wn = wv & 1;

  f32x4 acc[4][4];
#pragma unroll
  for (int fm = 0; fm < 4; ++fm)
#pragma unroll
    for (int fn = 0; fn < 4; ++fn) acc[fm][fn] = (f32x4)0.0f;

  const int srow = wv * 32 + (l >> 3);
  const int cg = (l & 7) ^ (srow & 7);
  const short* Ab = AO  + (size_t)(mt * 128 + srow) * 384 + cg * 8;
  const short* Bb = WoT + (size_t)(nt * 128 + srow) * 384 + cg * 8;

#define STAGE(KS, SEL) do {                                                  \
  _Pragma("unroll")                                                          \
  for (int i_ = 0; i_ < 4; ++i_) {                                           \
    gload_lds16(Ab + i_ * 3072 + (KS) * 64,                                  \
                lds + (SEL) * 16384 + (wv * 4 + i_) * 512);                  \
    gload_lds16(Bb + i_ * 3072 + (KS) * 64,                                  \
                lds + (SEL) * 16384 + 8192 + (wv * 4 + i_) * 512);           \
  } } while (0)

#define COMPUTE(SEL) do {                                                    \
  const short* Acur_ = lds + (SEL) * 16384;                                  \
  const short* Bcur_ = Acur_ + 8192;                                         \
  _Pragma("unroll")                                                          \
  for (int kk = 0; kk < 2; ++kk) {                                           \
    s16x8 af[4], bf[4];                                                      \
    _Pragma("unroll")                                                        \
    for (int f = 0; f < 4; ++f) {                                            \
      const int arow = wm * 64 + f * 16 + lr;                                \
      const int ac = (kk * 4 + lg) ^ (arow & 7);                             \
      af[f] = *(const s16x8*)(Acur_ + arow * 64 + ac * 8);                   \
      const int brow = wn * 64 + f * 16 + lr;                                \
      const int bc = (kk * 4 + lg) ^ (brow & 7);                             \
      bf[f] = *(const s16x8*)(Bcur_ + brow * 64 + bc * 8);                   \
    }                                                                        \
    _Pragma("unroll")                                                        \
    for (int fm = 0; fm < 4; ++fm)                                           \
      _Pragma("unroll")                                                      \
      for (int fn = 0; fn < 4; ++fn)                                         \
        acc[fm][fn] = MFMA16(af[fm], bf[fn], acc[fm][fn]);                   \
  } } while (0)

#define ITER(T, WN) do {                                                     \
  asm volatile("s_waitcnt vmcnt(" #WN ")" ::: "memory");                     \
  __builtin_amdgcn_s_barrier();                                              \
  COMPUTE((T) & 1);                                                          \
  asm volatile("s_waitcnt lgkmcnt(0)" ::: "memory");  /* WAR drain */        \
  __builtin_amdgcn_s_barrier();                                              \
  if ((T) + 2 < 6) STAGE((T) + 2, (T) & 1);                                  \
  } while (0)

  STAGE(0, 0);
  STAGE(1, 1);
  ITER(0, 8); ITER(1, 8); ITER(2, 8); ITER(3, 8); ITER(4, 8); ITER(5, 0);
#undef ITER
#undef COMPUTE
#undef STAGE

#pragma unroll
  for (int fn = 0; fn < 4; ++fn) {
    const int n = nt * 128 + wn * 64 + fn * 16 + lr;
    const float bias = bo[n];
#pragma unroll
    for (int fm = 0; fm < 4; ++fm) {
      const int m0 = mt * 128 + wm * 64 + fm * 16 + lg * 4;
#pragma unroll
      for (int r = 0; r < 4; ++r)
        out[(size_t)(m0 + r) * 384 + n] = acc[fm][fn][r] + bias;
    }
  }
}

extern "C" void kernel_launch(void* const* d_in, const int* in_sizes, int n_in,
                              void* d_out, int out_size, void* d_ws, size_t ws_size,
                              hipStream_t stream)
{
  const float* X    = (const float*)d_in[0];
  const float* Wqkv = (const float*)d_in[1];
  const float* posb = (const float*)d_in[2];
  const float* Wo   = (const float*)d_in[3];
  const float* bo   = (const float*)d_in[4];
  const int*   relp = (const int*)d_in[5];
  float* out = (float*)d_out;

  // workspace carve — ~155.5 MB
  char* ws = (char*)d_ws;
  short* WqkvT = (short*)(ws);                 //   884,736 B
  short* WoT   = (short*)(ws + 884736);        //   294,912 B
  float* biasF = (float*)(ws + 1179648);       //   196,608 B
  short* Xbf   = (short*)(ws + 1376256);       // 77,070,336 B [100352][384]
  short* AO    = (short*)(ws + 78446592);      // 77,070,336 B [100352][384]

  prep_kernel<<<2496, 256, 0, stream>>>(Wqkv, Wo, posb, relp, WqkvT, WoT, biasF);
  xcvt_kernel<<<2048, 256, 0, stream>>>(X, Xbf);
  qkv_attn<<<4704, 256, 0, stream>>>(Xbf, WqkvT, biasF, AO);
  proj_kernel<<<2352, 256, 0, stream>>>(AO, WoT, bo, out);
}

// Round 17
// 344.708 us; speedup vs baseline: 2.5036x; 2.5036x over previous
//
#include <hip/hip_runtime.h>
#include <hip/hip_bf16.h>

typedef float f32x4 __attribute__((ext_vector_type(4)));
typedef short s16x8 __attribute__((ext_vector_type(8)));

#define MFMA16(A,B,C) __builtin_amdgcn_mfma_f32_16x16x32_bf16((A),(B),(C),0,0,0)

// Hardware RNE f32->bf16 (v_cvt_pk_bf16_f32 when paired).
__device__ __forceinline__ short f2bf(float f) {
  return (short)__bfloat16_as_ushort(__float2bfloat16(f));
}

__device__ __forceinline__ void gload_lds16(const void* g, void* l) {
  __builtin_amdgcn_global_load_lds(
      (const __attribute__((address_space(1))) unsigned*)g,
      (__attribute__((address_space(3))) unsigned*)l, 16, 0, 0);
}

// ---------------- prep: transpose weights to bf16[N][K], gather bias table ----
__global__ __launch_bounds__(256) void prep_kernel(
    const float* __restrict__ Wqkv, const float* __restrict__ Wo,
    const float* __restrict__ posb, const int* __restrict__ relp,
    short* __restrict__ WqkvT, short* __restrict__ WoT, float* __restrict__ biasF)
{
  int i = blockIdx.x * 256 + threadIdx.x;
  if (i < 1152 * 384) {
    int n = i / 384, k = i % 384;
    WqkvT[i] = f2bf(Wqkv[k * 1152 + n]);
  } else if (i < 1152 * 384 + 384 * 384) {
    int j = i - 1152 * 384;
    int n = j / 384, k = j % 384;
    WoT[j] = f2bf(Wo[k * 384 + n]);
  } else {
    int j = i - (1152 * 384 + 384 * 384);    // j < 12*64*64 = 49152
    int h = j >> 12, qk = j & 4095;
    biasF[j] = posb[h * 16129 + relp[qk]];
  }
}

// ---------------- X f32 -> bf16 (memory-bound, vectorized) --------------------
__global__ __launch_bounds__(256) void xcvt_kernel(
    const float* __restrict__ X, short* __restrict__ Xbf)
{
  const int n8 = 4816896;                  // 38,535,168 / 8
  for (int i = blockIdx.x * 256 + threadIdx.x; i < n8; i += gridDim.x * 256) {
    float4 a = *(const float4*)(X + (size_t)i * 8);
    float4 b = *(const float4*)(X + (size_t)i * 8 + 4);
    s16x8 p;
    p[0] = f2bf(a.x); p[1] = f2bf(a.y); p[2] = f2bf(a.z); p[3] = f2bf(a.w);
    p[4] = f2bf(b.x); p[5] = f2bf(b.y); p[6] = f2bf(b.z); p[7] = f2bf(b.w);
    *(s16x8*)(Xbf + (size_t)i * 8) = p;
  }
}

// ---------------- fused QKV GEMM + attention (2 heads / block) ----------------
// R16 structure (B operand per-lane from L2-hot WqkvT, A via gload_lds dbuf,
// LDS 39KB) with the VGPR clamp REMOVED: R16's __launch_bounds__(256,4)
// forced 64 VGPRs -> acc[6][4] spilled to scratch (FETCH 1.1GB, 740us).
// Natural allocation (~128-150 VGPR) gives 3-4 blocks/CU via the LDS cut.
__global__ __launch_bounds__(256) void qkv_attn(
    const short* __restrict__ Xbf, const short* __restrict__ WqkvT,
    const float* __restrict__ biasF, short* __restrict__ AO)
{
  __shared__ short lds[19968];   // A dbuf: sel*8192 (32KB); attn scratch reuses
  const int bid = blockIdx.x;
  const int wg = (bid & 7) * 588 + (bid >> 3);   // XCD swizzle (4704 = 8*588)
  const int hg = wg % 6, mt = wg / 6;
  const int t = threadIdx.x;
  const int wv = t >> 6, l = t & 63, lr = l & 15, lg = l >> 4;
  const int wm = wv >> 1, wn = wv & 1;

  f32x4 acc[6][4];               // [fn: q0,q1,k0,k1,v0,v1][fm: token block]
#pragma unroll
  for (int fn = 0; fn < 6; ++fn)
#pragma unroll
    for (int fm = 0; fm < 4; ++fm) acc[fn][fm] = (f32x4)0.0f;

  const int cgs = (l & 7) ^ (l >> 3);
  const short* AbT = Xbf + (size_t)(mt * 128 + wv * 32 + (l >> 3)) * 384 + cgs * 8;
  // per-lane B fragment bases: row = (fn>>1)*384 + hg*64 + wn*32 + (fn&1)*16+lr
  const short* Bb[6];
#pragma unroll
  for (int fn = 0; fn < 6; ++fn)
    Bb[fn] = WqkvT + (size_t)((fn >> 1) * 384 + hg * 64 + wn * 32
                              + (fn & 1) * 16 + lr) * 384 + lg * 8;

#define STAGE(KS, SEL) do {                                                  \
  _Pragma("unroll")                                                          \
  for (int i_ = 0; i_ < 4; ++i_)                                             \
    gload_lds16(AbT + i_ * 3072 + (KS) * 64,                                 \
                lds + (SEL) * 8192 + (wv * 4 + i_) * 512);                   \
  } while (0)

#define COMPUTE(T) do {                                                      \
  const short* Acur_ = lds + ((T) & 1) * 8192;                               \
  _Pragma("unroll")                                                          \
  for (int kk = 0; kk < 2; ++kk) {                                           \
    s16x8 af[4], bq[6];                                                      \
    _Pragma("unroll")                                                        \
    for (int fn = 0; fn < 6; ++fn)                                           \
      bq[fn] = *(const s16x8*)(Bb[fn] + (T) * 64 + kk * 32);                 \
    _Pragma("unroll")                                                        \
    for (int f = 0; f < 4; ++f) {                                            \
      const int arow = wm * 64 + f * 16 + lr;                                \
      const int ac = (kk * 4 + lg) ^ (arow & 7);                             \
      af[f] = *(const s16x8*)(Acur_ + arow * 64 + ac * 8);                   \
    }                                                                        \
    _Pragma("unroll")                                                        \
    for (int fn = 0; fn < 6; ++fn)                                           \
      _Pragma("unroll")                                                      \
      for (int fm = 0; fm < 4; ++fm)                                         \
        acc[fn][fm] = MFMA16(bq[fn], af[fm], acc[fn][fm]);   /* W·X^T */     \
  } } while (0)

#define ITER(T, WN) do {                                                     \
  asm volatile("s_waitcnt vmcnt(" #WN ")" ::: "memory");                     \
  __builtin_amdgcn_s_barrier();                                              \
  COMPUTE(T);                                                                \
  asm volatile("s_waitcnt lgkmcnt(0)" ::: "memory");  /* WAR drain */        \
  __builtin_amdgcn_s_barrier();                                              \
  if ((T) + 2 < 6) STAGE((T) + 2, (T) & 1);                                  \
  } while (0)

  STAGE(0, 0);
  STAGE(1, 1);
  ITER(0, 4); ITER(1, 4); ITER(2, 4); ITER(3, 4); ITER(4, 4); ITER(5, 0);
#undef ITER
#undef COMPUTE
#undef STAGE

  // final ITER's lgkm(0)+barrier drained all GEMM LDS reads block-wide;
  // per-wave attn scratch below may overwrite the A dbuf region.

  // ---- attention, one (window, head) per wave; Q/K stay in registers ----
  const int w = mt * 2 + wm, h = hg * 2 + wn;
  short* Vts = lds + wv * 4992;          // [32][76] V^T (stride 76: no 4-way)
  short* Os  = Vts + 2432;               // [64][40] epilogue staging

  // V scatter: Vts[d][tok], d = fv*16+lg*4+r, tok = fm*16+lr
#pragma unroll
  for (int fv = 0; fv < 2; ++fv)
#pragma unroll
    for (int fm = 0; fm < 4; ++fm)
#pragma unroll
      for (int r = 0; r < 4; ++r)
        Vts[(fv * 16 + lg * 4 + r) * 76 + fm * 16 + lr] =
            f2bf(acc[4 + fv][fm][r]);

  // pack K (A-op: lane=row kt) and Q (B-op: lane=col q) frags in-register;
  // slot j -> d = 16*(j>>2) + 4*lg + (j&3)  (same sigma on both operands)
  s16x8 ka[4], qb[4];
#pragma unroll
  for (int f = 0; f < 4; ++f) {
    s16x8 tk, tq;
#pragma unroll
    for (int j = 0; j < 8; ++j) {
      tk[j] = f2bf(acc[2 + (j >> 2)][f][j & 3]);
      tq[j] = f2bf(acc[0 + (j >> 2)][f][j & 3]);
    }
    ka[f] = tk; qb[f] = tq;
  }

  // S^T = K·Q^T  (rows kt, cols q), K-dim 32
  f32x4 st[4][4];
#pragma unroll
  for (int fk = 0; fk < 4; ++fk)
#pragma unroll
    for (int fq = 0; fq < 4; ++fq)
      st[fk][fq] = MFMA16(ka[fk], qb[fq], (f32x4)0.0f);

  // scale + bias + softmax over kt (per q column, per-lane + shfl 16/32)
  const float* bh = biasF + h * 4096;
#pragma unroll
  for (int fq = 0; fq < 4; ++fq) {
    const int q = fq * 16 + lr;
    float4 bv[4];
#pragma unroll
    for (int fk = 0; fk < 4; ++fk)
      bv[fk] = *(const float4*)(bh + q * 64 + fk * 16 + lg * 4);
    float mx = -3.0e38f;
#pragma unroll
    for (int fk = 0; fk < 4; ++fk)
#pragma unroll
      for (int r = 0; r < 4; ++r) {
        float v = st[fk][fq][r] * 0.17677669529663687f + ((const float*)&bv[fk])[r];
        st[fk][fq][r] = v;
        mx = fmaxf(mx, v);
      }
    mx = fmaxf(mx, __shfl_xor(mx, 16));
    mx = fmaxf(mx, __shfl_xor(mx, 32));
    float sm = 0.0f;
#pragma unroll
    for (int fk = 0; fk < 4; ++fk)
#pragma unroll
      for (int r = 0; r < 4; ++r) {
        float e = __expf(st[fk][fq][r] - mx);
        st[fk][fq][r] = e;
        sm += e;
      }
    sm += __shfl_xor(sm, 16);
    sm += __shfl_xor(sm, 32);
    const float inv = 1.0f / sm;
#pragma unroll
    for (int fk = 0; fk < 4; ++fk)
#pragma unroll
      for (int r = 0; r < 4; ++r) st[fk][fq][r] *= inv;
  }

  // O^T = V^T · P^T ; sigma(g,j)=32kb+16(j>>2)+4g+(j&3) on both operands
  s16x8 va[2][2];
#pragma unroll
  for (int fd = 0; fd < 2; ++fd)
#pragma unroll
    for (int kb = 0; kb < 2; ++kb) {
      short4 v0 = *(const short4*)(Vts + (fd * 16 + lr) * 76 + kb * 32 + lg * 4);
      short4 v1 = *(const short4*)(Vts + (fd * 16 + lr) * 76 + kb * 32 + 16 + lg * 4);
      s16x8 tv;
      tv[0] = v0.x; tv[1] = v0.y; tv[2] = v0.z; tv[3] = v0.w;
      tv[4] = v1.x; tv[5] = v1.y; tv[6] = v1.z; tv[7] = v1.w;
      va[fd][kb] = tv;
    }
  f32x4 ot[2][4];
#pragma unroll
  for (int fd = 0; fd < 2; ++fd)
#pragma unroll
    for (int fq = 0; fq < 4; ++fq) ot[fd][fq] = (f32x4)0.0f;
#pragma unroll
  for (int kb = 0; kb < 2; ++kb)
#pragma unroll
    for (int fq = 0; fq < 4; ++fq) {
      s16x8 pb;
#pragma unroll
      for (int j = 0; j < 8; ++j)
        pb[j] = f2bf(st[2 * kb + (j >> 2)][fq][j & 3]);   // lane-local repack
#pragma unroll
      for (int fd = 0; fd < 2; ++fd)
        ot[fd][fq] = MFMA16(va[fd][kb], pb, ot[fd][fq]);
    }

  // epilogue: stage O [q][d] in Os, write coalesced 64B rows
#pragma unroll
  for (int fd = 0; fd < 2; ++fd)
#pragma unroll
    for (int fq = 0; fq < 4; ++fq)
#pragma unroll
      for (int r = 0; r < 4; ++r)
        Os[(fq * 16 + lr) * 40 + fd * 16 + lg * 4 + r] = f2bf(ot[fd][fq][r]);
  short* dst = AO + ((size_t)w * 64 + l) * 384 + h * 32;
  int4 o0 = *(const int4*)(Os + l * 40);
  int4 o1 = *(const int4*)(Os + l * 40 + 8);
  int4 o2 = *(const int4*)(Os + l * 40 + 16);
  int4 o3 = *(const int4*)(Os + l * 40 + 24);
  *(int4*)(dst)      = o0;
  *(int4*)(dst + 8)  = o1;
  *(int4*)(dst + 16) = o2;
  *(int4*)(dst + 24) = o3;
}

// ---------------- output projection: out = AO(bf16) @ Wo + bo, f32 out --------
// R7-proven BK=64 2-deep counted-vmcnt pipeline.
__global__ __launch_bounds__(256) void proj_kernel(
    const short* __restrict__ AO, const short* __restrict__ WoT,
    const float* __restrict__ bo, float* __restrict__ out)
{
  __shared__ short lds[32768];
  const int bid = blockIdx.x;
  const int wg = (bid & 7) * 294 + (bid >> 3);   // XCD swizzle (2352 = 8*294)
  const int nt = wg % 3, mt = wg / 3;
  const int t = threadIdx.x;
  const int wv = t >> 6, l = t & 63, lr = l & 15, lg = l >> 4;
  const int wm = wv >> 1, wn = wv & 1;

  f32x4 acc[4][4];
#pragma unroll
  for (int fm = 0; fm < 4; ++fm)
#pragma unroll
    for (int fn = 0; fn < 4; ++fn) acc[fm][fn] = (f32x4)0.0f;

  const int srow = wv * 32 + (l >> 3);
  const int cg = (l & 7) ^ (srow & 7);
  const short* Ab = AO  + (size_t)(mt * 128 + srow) * 384 + cg * 8;
  const short* Bb = WoT + (size_t)(nt * 128 + srow) * 384 + cg * 8;

#define STAGE(KS, SEL) do {                                                  \
  _Pragma("unroll")                                                          \
  for (int i_ = 0; i_ < 4; ++i_) {                                           \
    gload_lds16(Ab + i_ * 3072 + (KS) * 64,                                  \
                lds + (SEL) * 16384 + (wv * 4 + i_) * 512);                  \
    gload_lds16(Bb + i_ * 3072 + (KS) * 64,                                  \
                lds + (SEL) * 16384 + 8192 + (wv * 4 + i_) * 512);           \
  } } while (0)

#define COMPUTE(SEL) do {                                                    \
  const short* Acur_ = lds + (SEL) * 16384;                                  \
  const short* Bcur_ = Acur_ + 8192;                                         \
  _Pragma("unroll")                                                          \
  for (int kk = 0; kk < 2; ++kk) {                                           \
    s16x8 af[4], bf[4];                                                      \
    _Pragma("unroll")                                                        \
    for (int f = 0; f < 4; ++f) {                                            \
      const int arow = wm * 64 + f * 16 + lr;                                \
      const int ac = (kk * 4 + lg) ^ (arow & 7);                             \
      af[f] = *(const s16x8*)(Acur_ + arow * 64 + ac * 8);                   \
      const int brow = wn * 64 + f * 16 + lr;                                \
      const int bc = (kk * 4 + lg) ^ (brow & 7);                             \
      bf[f] = *(const s16x8*)(Bcur_ + brow * 64 + bc * 8);                   \
    }                                                                        \
    _Pragma("unroll")                                                        \
    for (int fm = 0; fm < 4; ++fm)                                           \
      _Pragma("unroll")                                                      \
      for (int fn = 0; fn < 4; ++fn)                                         \
        acc[fm][fn] = MFMA16(af[fm], bf[fn], acc[fm][fn]);                   \
  } } while (0)

#define ITER(T, WN) do {                                                     \
  asm volatile("s_waitcnt vmcnt(" #WN ")" ::: "memory");                     \
  __builtin_amdgcn_s_barrier();                                              \
  COMPUTE((T) & 1);                                                          \
  asm volatile("s_waitcnt lgkmcnt(0)" ::: "memory");  /* WAR drain */        \
  __builtin_amdgcn_s_barrier();                                              \
  if ((T) + 2 < 6) STAGE((T) + 2, (T) & 1);                                  \
  } while (0)

  STAGE(0, 0);
  STAGE(1, 1);
  ITER(0, 8); ITER(1, 8); ITER(2, 8); ITER(3, 8); ITER(4, 8); ITER(5, 0);
#undef ITER
#undef COMPUTE
#undef STAGE

#pragma unroll
  for (int fn = 0; fn < 4; ++fn) {
    const int n = nt * 128 + wn * 64 + fn * 16 + lr;
    const float bias = bo[n];
#pragma unroll
    for (int fm = 0; fm < 4; ++fm) {
      const int m0 = mt * 128 + wm * 64 + fm * 16 + lg * 4;
#pragma unroll
      for (int r = 0; r < 4; ++r)
        out[(size_t)(m0 + r) * 384 + n] = acc[fm][fn][r] + bias;
    }
  }
}

extern "C" void kernel_launch(void* const* d_in, const int* in_sizes, int n_in,
                              void* d_out, int out_size, void* d_ws, size_t ws_size,
                              hipStream_t stream)
{
  const float* X    = (const float*)d_in[0];
  const float* Wqkv = (const float*)d_in[1];
  const float* posb = (const float*)d_in[2];
  const float* Wo   = (const float*)d_in[3];
  const float* bo   = (const float*)d_in[4];
  const int*   relp = (const int*)d_in[5];
  float* out = (float*)d_out;

  // workspace carve — ~155.5 MB
  char* ws = (char*)d_ws;
  short* WqkvT = (short*)(ws);                 //   884,736 B
  short* WoT   = (short*)(ws + 884736);        //   294,912 B
  float* biasF = (float*)(ws + 1179648);       //   196,608 B
  short* Xbf   = (short*)(ws + 1376256);       // 77,070,336 B [100352][384]
  short* AO    = (short*)(ws + 78446592);      // 77,070,336 B [100352][384]

  prep_kernel<<<2496, 256, 0, stream>>>(Wqkv, Wo, posb, relp, WqkvT, WoT, biasF);
  xcvt_kernel<<<2048, 256, 0, stream>>>(X, Xbf);
  qkv_attn<<<4704, 256, 0, stream>>>(Xbf, WqkvT, biasF, AO);
  proj_kernel<<<2352, 256, 0, stream>>>(AO, WoT, bo, out);
}

// Round 18
// 228.965 us; speedup vs baseline: 3.7692x; 1.5055x over previous
//
#include <hip/hip_runtime.h>
#include <hip/hip_bf16.h>

typedef float f32x4 __attribute__((ext_vector_type(4)));
typedef short s16x8 __attribute__((ext_vector_type(8)));

#define MFMA16(A,B,C) __builtin_amdgcn_mfma_f32_16x16x32_bf16((A),(B),(C),0,0,0)

// Hardware RNE f32->bf16 (v_cvt_pk_bf16_f32 when paired).
__device__ __forceinline__ short f2bf(float f) {
  return (short)__bfloat16_as_ushort(__float2bfloat16(f));
}

__device__ __forceinline__ void gload_lds16(const void* g, void* l) {
  __builtin_amdgcn_global_load_lds(
      (const __attribute__((address_space(1))) unsigned*)g,
      (__attribute__((address_space(3))) unsigned*)l, 16, 0, 0);
}

// ------- prep + xcvt merged: blocks [0,2496) do weight transpose + bias
// ------- gather; blocks [2496,4544) grid-stride convert X f32->bf16.
__global__ __launch_bounds__(256) void prep_cvt(
    const float* __restrict__ Wqkv, const float* __restrict__ Wo,
    const float* __restrict__ posb, const int* __restrict__ relp,
    const float* __restrict__ X,
    short* __restrict__ WqkvT, short* __restrict__ WoT,
    float* __restrict__ biasF, short* __restrict__ Xbf)
{
  const int bid = blockIdx.x;
  if (bid < 2496) {
    int i = bid * 256 + threadIdx.x;          // 2496*256 = 638,976 exactly
    if (i < 1152 * 384) {
      int n = i / 384, k = i % 384;
      WqkvT[i] = f2bf(Wqkv[k * 1152 + n]);
    } else if (i < 1152 * 384 + 384 * 384) {
      int j = i - 1152 * 384;
      int n = j / 384, k = j % 384;
      WoT[j] = f2bf(Wo[k * 384 + n]);
    } else {
      int j = i - (1152 * 384 + 384 * 384);   // j < 12*64*64 = 49152
      int h = j >> 12, qk = j & 4095;
      biasF[j] = posb[h * 16129 + relp[qk]];
    }
  } else {
    const int n8 = 4816896;                   // 38,535,168 / 8
    for (int i = (bid - 2496) * 256 + threadIdx.x; i < n8; i += 2048 * 256) {
      float4 a = *(const float4*)(X + (size_t)i * 8);
      float4 b = *(const float4*)(X + (size_t)i * 8 + 4);
      s16x8 p;
      p[0] = f2bf(a.x); p[1] = f2bf(a.y); p[2] = f2bf(a.z); p[3] = f2bf(a.w);
      p[4] = f2bf(b.x); p[5] = f2bf(b.y); p[6] = f2bf(b.z); p[7] = f2bf(b.w);
      *(s16x8*)(Xbf + (size_t)i * 8) = p;
    }
  }
}

// ---------------- fused QKV GEMM + attention (2 heads / block) ----------------
// R15-proven (232.6us total): swapped-operand GEMM acc' = W·X^T (A-op = W
// frags, B-op = X frags; both staged via gload_lds into 80KB LDS dbuf,
// 2-deep counted-vmcnt ITER, both-sides XOR involution). C' col=lane&15=token,
// row=n(d) -> Q/K packed lane-locally from acc (no LDS roundtrip), V via LDS
// transpose (stride 76). sigma''(lg,j)=16(j>>2)+4lg+(j&3) on both operands.
__global__ __launch_bounds__(256) void qkv_attn(
    const short* __restrict__ Xbf, const short* __restrict__ WqkvT,
    const float* __restrict__ biasF, short* __restrict__ AO)
{
  __shared__ short lds[40960];   // A: sel*8192 | B: 16384 + sel*12288 (shorts)
  const int bid = blockIdx.x;
  const int wg = (bid & 7) * 588 + (bid >> 3);   // XCD swizzle (4704 = 8*588)
  const int hg = wg % 6, mt = wg / 6;
  const int t = threadIdx.x;
  const int wv = t >> 6, l = t & 63, lr = l & 15, lg = l >> 4;
  const int wm = wv >> 1, wn = wv & 1;

  f32x4 acc[6][4];               // [fn: q0,q1,k0,k1,v0,v1][fm: token block]
#pragma unroll
  for (int fn = 0; fn < 6; ++fn)
#pragma unroll
    for (int fm = 0; fm < 4; ++fm) acc[fn][fm] = (f32x4)0.0f;

  const int cgs = (l & 7) ^ (l >> 3);
  const short* AbT = Xbf + (size_t)(mt * 128 + wv * 32 + (l >> 3)) * 384 + cgs * 8;
  const short* BbT[6];
#pragma unroll
  for (int j = 0; j < 6; ++j) {
    const int n0 = wv * 48 + j * 8 + (l >> 3);
    const int hl = n0 / 96, rem = n0 % 96;
    const int p = rem >> 5, d = rem & 31;
    BbT[j] = WqkvT + (size_t)(p * 384 + hg * 64 + hl * 32 + d) * 384 + cgs * 8;
  }

#define STAGE(KS, SEL) do {                                                  \
  _Pragma("unroll")                                                          \
  for (int i_ = 0; i_ < 4; ++i_)                                             \
    gload_lds16(AbT + i_ * 3072 + (KS) * 64,                                 \
                lds + (SEL) * 8192 + (wv * 4 + i_) * 512);                   \
  _Pragma("unroll")                                                          \
  for (int j_ = 0; j_ < 6; ++j_)                                             \
    gload_lds16(BbT[j_] + (KS) * 64,                                         \
                lds + 16384 + (SEL) * 12288 + (wv * 6 + j_) * 512);          \
  } while (0)

#define COMPUTE(SEL) do {                                                    \
  const short* Acur_ = lds + (SEL) * 8192;                                   \
  const short* Bcur_ = lds + 16384 + (SEL) * 12288;                          \
  _Pragma("unroll")                                                          \
  for (int kk = 0; kk < 2; ++kk) {                                           \
    s16x8 af[4], bq[6];                                                      \
    _Pragma("unroll")                                                        \
    for (int f = 0; f < 4; ++f) {                                            \
      const int arow = wm * 64 + f * 16 + lr;                                \
      const int ac = (kk * 4 + lg) ^ (arow & 7);                             \
      af[f] = *(const s16x8*)(Acur_ + arow * 64 + ac * 8);                   \
    }                                                                        \
    _Pragma("unroll")                                                        \
    for (int fn = 0; fn < 6; ++fn) {                                         \
      const int brow = wn * 96 + fn * 16 + lr;                               \
      const int bc = (kk * 4 + lg) ^ (brow & 7);                             \
      bq[fn] = *(const s16x8*)(Bcur_ + brow * 64 + bc * 8);                  \
    }                                                                        \
    _Pragma("unroll")                                                        \
    for (int fn = 0; fn < 6; ++fn)                                           \
      _Pragma("unroll")                                                      \
      for (int fm = 0; fm < 4; ++fm)                                         \
        acc[fn][fm] = MFMA16(bq[fn], af[fm], acc[fn][fm]);   /* W·X^T */     \
  } } while (0)

#define ITER(T, WN) do {                                                     \
  asm volatile("s_waitcnt vmcnt(" #WN ")" ::: "memory");                     \
  __builtin_amdgcn_s_barrier();                                              \
  COMPUTE((T) & 1);                                                          \
  asm volatile("s_waitcnt lgkmcnt(0)" ::: "memory");  /* WAR drain */        \
  __builtin_amdgcn_s_barrier();                                              \
  if ((T) + 2 < 6) STAGE((T) + 2, (T) & 1);                                  \
  } while (0)

  STAGE(0, 0);
  STAGE(1, 1);
  ITER(0, 10); ITER(1, 10); ITER(2, 10); ITER(3, 10); ITER(4, 10); ITER(5, 0);
#undef ITER
#undef COMPUTE
#undef STAGE

  // final ITER's lgkm(0)+barrier drained all GEMM LDS reads block-wide;
  // per-wave attn scratch below may overwrite the staging region.

  // ---- attention, one (window, head) per wave; Q/K stay in registers ----
  const int w = mt * 2 + wm, h = hg * 2 + wn;
  short* Vts = lds + wv * 4992;          // [32][76] V^T (stride 76: no 4-way)
  short* Os  = Vts + 2432;               // [64][40] epilogue staging

  // V scatter: Vts[d][tok], d = fv*16+lg*4+r, tok = fm*16+lr
#pragma unroll
  for (int fv = 0; fv < 2; ++fv)
#pragma unroll
    for (int fm = 0; fm < 4; ++fm)
#pragma unroll
      for (int r = 0; r < 4; ++r)
        Vts[(fv * 16 + lg * 4 + r) * 76 + fm * 16 + lr] =
            f2bf(acc[4 + fv][fm][r]);

  // pack K (A-op: lane=row kt) and Q (B-op: lane=col q) frags in-register;
  // slot j -> d = 16*(j>>2) + 4*lg + (j&3)  (same sigma on both operands)
  s16x8 ka[4], qb[4];
#pragma unroll
  for (int f = 0; f < 4; ++f) {
    s16x8 tk, tq;
#pragma unroll
    for (int j = 0; j < 8; ++j) {
      tk[j] = f2bf(acc[2 + (j >> 2)][f][j & 3]);
      tq[j] = f2bf(acc[0 + (j >> 2)][f][j & 3]);
    }
    ka[f] = tk; qb[f] = tq;
  }

  // S^T = K·Q^T  (rows kt, cols q), K-dim 32
  f32x4 st[4][4];
#pragma unroll
  for (int fk = 0; fk < 4; ++fk)
#pragma unroll
    for (int fq = 0; fq < 4; ++fq)
      st[fk][fq] = MFMA16(ka[fk], qb[fq], (f32x4)0.0f);

  // scale + bias + softmax over kt (per q column, per-lane + shfl 16/32)
  const float* bh = biasF + h * 4096;
#pragma unroll
  for (int fq = 0; fq < 4; ++fq) {
    const int q = fq * 16 + lr;
    float4 bv[4];
#pragma unroll
    for (int fk = 0; fk < 4; ++fk)
      bv[fk] = *(const float4*)(bh + q * 64 + fk * 16 + lg * 4);
    float mx = -3.0e38f;
#pragma unroll
    for (int fk = 0; fk < 4; ++fk)
#pragma unroll
      for (int r = 0; r < 4; ++r) {
        float v = st[fk][fq][r] * 0.17677669529663687f + ((const float*)&bv[fk])[r];
        st[fk][fq][r] = v;
        mx = fmaxf(mx, v);
      }
    mx = fmaxf(mx, __shfl_xor(mx, 16));
    mx = fmaxf(mx, __shfl_xor(mx, 32));
    float sm = 0.0f;
#pragma unroll
    for (int fk = 0; fk < 4; ++fk)
#pragma unroll
      for (int r = 0; r < 4; ++r) {
        float e = __expf(st[fk][fq][r] - mx);
        st[fk][fq][r] = e;
        sm += e;
      }
    sm += __shfl_xor(sm, 16);
    sm += __shfl_xor(sm, 32);
    const float inv = 1.0f / sm;
#pragma unroll
    for (int fk = 0; fk < 4; ++fk)
#pragma unroll
      for (int r = 0; r < 4; ++r) st[fk][fq][r] *= inv;
  }

  // O^T = V^T · P^T ; sigma(g,j)=32kb+16(j>>2)+4g+(j&3) on both operands
  s16x8 va[2][2];
#pragma unroll
  for (int fd = 0; fd < 2; ++fd)
#pragma unroll
    for (int kb = 0; kb < 2; ++kb) {
      short4 v0 = *(const short4*)(Vts + (fd * 16 + lr) * 76 + kb * 32 + lg * 4);
      short4 v1 = *(const short4*)(Vts + (fd * 16 + lr) * 76 + kb * 32 + 16 + lg * 4);
      s16x8 tv;
      tv[0] = v0.x; tv[1] = v0.y; tv[2] = v0.z; tv[3] = v0.w;
      tv[4] = v1.x; tv[5] = v1.y; tv[6] = v1.z; tv[7] = v1.w;
      va[fd][kb] = tv;
    }
  f32x4 ot[2][4];
#pragma unroll
  for (int fd = 0; fd < 2; ++fd)
#pragma unroll
    for (int fq = 0; fq < 4; ++fq) ot[fd][fq] = (f32x4)0.0f;
#pragma unroll
  for (int kb = 0; kb < 2; ++kb)
#pragma unroll
    for (int fq = 0; fq < 4; ++fq) {
      s16x8 pb;
#pragma unroll
      for (int j = 0; j < 8; ++j)
        pb[j] = f2bf(st[2 * kb + (j >> 2)][fq][j & 3]);   // lane-local repack
#pragma unroll
      for (int fd = 0; fd < 2; ++fd)
        ot[fd][fq] = MFMA16(va[fd][kb], pb, ot[fd][fq]);
    }

  // epilogue: stage O [q][d] in Os, write coalesced 64B rows
#pragma unroll
  for (int fd = 0; fd < 2; ++fd)
#pragma unroll
    for (int fq = 0; fq < 4; ++fq)
#pragma unroll
      for (int r = 0; r < 4; ++r)
        Os[(fq * 16 + lr) * 40 + fd * 16 + lg * 4 + r] = f2bf(ot[fd][fq][r]);
  short* dst = AO + ((size_t)w * 64 + l) * 384 + h * 32;
  int4 o0 = *(const int4*)(Os + l * 40);
  int4 o1 = *(const int4*)(Os + l * 40 + 8);
  int4 o2 = *(const int4*)(Os + l * 40 + 16);
  int4 o3 = *(const int4*)(Os + l * 40 + 24);
  *(int4*)(dst)      = o0;
  *(int4*)(dst + 8)  = o1;
  *(int4*)(dst + 16) = o2;
  *(int4*)(dst + 24) = o3;
}

// ---------------- output projection: out = AO(bf16) @ Wo + bo, f32 out --------
// R7-proven BK=64 2-deep counted-vmcnt pipeline.
__global__ __launch_bounds__(256) void proj_kernel(
    const short* __restrict__ AO, const short* __restrict__ WoT,
    const float* __restrict__ bo, float* __restrict__ out)
{
  __shared__ short lds[32768];
  const int bid = blockIdx.x;
  const int wg = (bid & 7) * 294 + (bid >> 3);   // XCD swizzle (2352 = 8*294)
  const int nt = wg % 3, mt = wg / 3;
  const int t = threadIdx.x;
  const int wv = t >> 6, l = t & 63, lr = l & 15, lg = l >> 4;
  const int wm = wv >> 1, wn = wv & 1;

  f32x4 acc[4][4];
#pragma unroll
  for (int fm = 0; fm < 4; ++fm)
#pragma unroll
    for (int fn = 0; fn < 4; ++fn) acc[fm][fn] = (f32x4)0.0f;

  const int srow = wv * 32 + (l >> 3);
  const int cg = (l & 7) ^ (srow & 7);
  const short* Ab = AO  + (size_t)(mt * 128 + srow) * 384 + cg * 8;
  const short* Bb = WoT + (size_t)(nt * 128 + srow) * 384 + cg * 8;

#define STAGE(KS, SEL) do {                                                  \
  _Pragma("unroll")                                                          \
  for (int i_ = 0; i_ < 4; ++i_) {                                           \
    gload_lds16(Ab + i_ * 3072 + (KS) * 64,                                  \
                lds + (SEL) * 16384 + (wv * 4 + i_) * 512);                  \
    gload_lds16(Bb + i_ * 3072 + (KS) * 64,                                  \
                lds + (SEL) * 16384 + 8192 + (wv * 4 + i_) * 512);           \
  } } while (0)

#define COMPUTE(SEL) do {                                                    \
  const short* Acur_ = lds + (SEL) * 16384;                                  \
  const short* Bcur_ = Acur_ + 8192;                                         \
  _Pragma("unroll")                                                          \
  for (int kk = 0; kk < 2; ++kk) {                                           \
    s16x8 af[4], bf[4];                                                      \
    _Pragma("unroll")                                                        \
    for (int f = 0; f < 4; ++f) {                                            \
      const int arow = wm * 64 + f * 16 + lr;                                \
      const int ac = (kk * 4 + lg) ^ (arow & 7);                             \
      af[f] = *(const s16x8*)(Acur_ + arow * 64 + ac * 8);                   \
      const int brow = wn * 64 + f * 16 + lr;                                \
      const int bc = (kk * 4 + lg) ^ (brow & 7);                             \
      bf[f] = *(const s16x8*)(Bcur_ + brow * 64 + bc * 8);                   \
    }                                                                        \
    _Pragma("unroll")                                                        \
    for (int fm = 0; fm < 4; ++fm)                                           \
      _Pragma("unroll")                                                      \
      for (int fn = 0; fn < 4; ++fn)                                         \
        acc[fm][fn] = MFMA16(af[fm], bf[fn], acc[fm][fn]);                   \
  } } while (0)

#define ITER(T, WN) do {                                                     \
  asm volatile("s_waitcnt vmcnt(" #WN ")" ::: "memory");                     \
  __builtin_amdgcn_s_barrier();                                              \
  COMPUTE((T) & 1);                                                          \
  asm volatile("s_waitcnt lgkmcnt(0)" ::: "memory");  /* WAR drain */        \
  __builtin_amdgcn_s_barrier();                                              \
  if ((T) + 2 < 6) STAGE((T) + 2, (T) & 1);                                  \
  } while (0)

  STAGE(0, 0);
  STAGE(1, 1);
  ITER(0, 8); ITER(1, 8); ITER(2, 8); ITER(3, 8); ITER(4, 8); ITER(5, 0);
#undef ITER
#undef COMPUTE
#undef STAGE

#pragma unroll
  for (int fn = 0; fn < 4; ++fn) {
    const int n = nt * 128 + wn * 64 + fn * 16 + lr;
    const float bias = bo[n];
#pragma unroll
    for (int fm = 0; fm < 4; ++fm) {
      const int m0 = mt * 128 + wm * 64 + fm * 16 + lg * 4;
#pragma unroll
      for (int r = 0; r < 4; ++r)
        out[(size_t)(m0 + r) * 384 + n] = acc[fm][fn][r] + bias;
    }
  }
}

extern "C" void kernel_launch(void* const* d_in, const int* in_sizes, int n_in,
                              void* d_out, int out_size, void* d_ws, size_t ws_size,
                              hipStream_t stream)
{
  const float* X    = (const float*)d_in[0];
  const float* Wqkv = (const float*)d_in[1];
  const float* posb = (const float*)d_in[2];
  const float* Wo   = (const float*)d_in[3];
  const float* bo   = (const float*)d_in[4];
  const int*   relp = (const int*)d_in[5];
  float* out = (float*)d_out;

  // workspace carve — ~155.5 MB
  char* ws = (char*)d_ws;
  short* WqkvT = (short*)(ws);                 //   884,736 B
  short* WoT   = (short*)(ws + 884736);        //   294,912 B
  float* biasF = (float*)(ws + 1179648);       //   196,608 B
  short* Xbf   = (short*)(ws + 1376256);       // 77,070,336 B [100352][384]
  short* AO    = (short*)(ws + 78446592);      // 77,070,336 B [100352][384]

  prep_cvt<<<4544, 256, 0, stream>>>(Wqkv, Wo, posb, relp, X,
                                     WqkvT, WoT, biasF, Xbf);
  qkv_attn<<<4704, 256, 0, stream>>>(Xbf, WqkvT, biasF, AO);
  proj_kernel<<<2352, 256, 0, stream>>>(AO, WoT, bo, out);
}

// Round 19
// 221.224 us; speedup vs baseline: 3.9011x; 1.0350x over previous
//
#include <hip/hip_runtime.h>
#include <hip/hip_bf16.h>

typedef float f32x4 __attribute__((ext_vector_type(4)));
typedef short s16x8 __attribute__((ext_vector_type(8)));

#define MFMA16(A,B,C) __builtin_amdgcn_mfma_f32_16x16x32_bf16((A),(B),(C),0,0,0)

// Hardware RNE f32->bf16 (v_cvt_pk_bf16_f32 when paired).
__device__ __forceinline__ short f2bf(float f) {
  return (short)__bfloat16_as_ushort(__float2bfloat16(f));
}

__device__ __forceinline__ void gload_lds16(const void* g, void* l) {
  __builtin_amdgcn_global_load_lds(
      (const __attribute__((address_space(1))) unsigned*)g,
      (__attribute__((address_space(3))) unsigned*)l, 16, 0, 0);
}

// ---------------- prep: weights -> bf16[N][K], gather bias table --------------
__global__ __launch_bounds__(256) void prep_kernel(
    const float* __restrict__ Wqkv, const float* __restrict__ Wo,
    const float* __restrict__ posb, const int* __restrict__ relp,
    short* __restrict__ WqkvT, short* __restrict__ WoT, float* __restrict__ biasF)
{
  int i = blockIdx.x * 256 + threadIdx.x;     // 2496*256 = 638,976 exactly
  if (i < 1152 * 384) {
    int n = i / 384, k = i % 384;
    WqkvT[i] = f2bf(Wqkv[k * 1152 + n]);
  } else if (i < 1152 * 384 + 384 * 384) {
    int j = i - 1152 * 384;
    int n = j / 384, k = j % 384;
    WoT[j] = f2bf(Wo[k * 384 + n]);
  } else {
    int j = i - (1152 * 384 + 384 * 384);     // j < 12*64*64 = 49152
    int h = j >> 12, qk = j & 4095;
    biasF[j] = posb[h * 16129 + relp[qk]];
  }
}

// ---------------- fused X-convert + QKV GEMM + attention (2 heads / block) ----
// R18 (R15-proven) structure with the A operand loaded DIRECTLY from f32 X:
// reg-staged (8x float4 -> cvt -> 4x ds_write_b128), deleting prep_cvt's X
// pass (231MB). Fix for R10's failure: ALOAD(T+3) issues at bottom of iter T
// and is written at bottom of iter T+1 -> one FULL iteration (~2400cy) of
// latency cover. Per-wave vmcnt walk (ALOAD=8, STAGE_B=6):
//   prologue A0 A1 B0 B1 -> vmcnt(20) AWRITE(a0); vmcnt(12) AWRITE(a1);
//   ALOAD(a0,2); lgkm(0)
//   tops: 14,14,14,14,6,0 ; bottoms: STAGE_B(T+2); vmcnt(6) [A for T+2 done,
//   forces prior B done too]; AWRITE; ALOAD(T+3); lgkm(0).
// WAR safety: AWRITE targets buf(T&1) only after iter T's lgkm(0)+barrier
// drained all reads of that buffer (R7-proven ordering).
__global__ __launch_bounds__(256) void qkv_attn(
    const float* __restrict__ X, const short* __restrict__ WqkvT,
    const float* __restrict__ biasF, short* __restrict__ AO)
{
  __shared__ short lds[40960];   // A: sel*8192 | B: 16384 + sel*12288 (shorts)
  const int bid = blockIdx.x;
  const int wg = (bid & 7) * 588 + (bid >> 3);   // XCD swizzle (4704 = 8*588)
  const int hg = wg % 6, mt = wg / 6;
  const int t = threadIdx.x;
  const int wv = t >> 6, l = t & 63, lr = l & 15, lg = l >> 4;
  const int wm = wv >> 1, wn = wv & 1;

  f32x4 acc[6][4];               // [fn: q0,q1,k0,k1,v0,v1][fm: token block]
#pragma unroll
  for (int fn = 0; fn < 6; ++fn)
#pragma unroll
    for (int fm = 0; fm < 4; ++fm) acc[fn][fm] = (f32x4)0.0f;

  const int cgs = (l & 7) ^ (l >> 3);
  const float* Axf = X + (size_t)(mt * 128 + wv * 32 + (l >> 3)) * 384 + cgs * 8;
  const int adst = (wv * 32 + (l >> 3)) * 64 + (l & 7) * 8;  // + i*512, shorts
  const short* BbT[6];
#pragma unroll
  for (int j = 0; j < 6; ++j) {
    const int n0 = wv * 48 + j * 8 + (l >> 3);
    const int hl = n0 / 96, rem = n0 % 96;
    const int p = rem >> 5, d = rem & 31;
    BbT[j] = WqkvT + (size_t)(p * 384 + hg * 64 + hl * 32 + d) * 384 + cgs * 8;
  }

  float4 a0[8], a1[8];

#define ALOAD(SET, KS) do {                                                  \
  _Pragma("unroll")                                                          \
  for (int i_ = 0; i_ < 4; ++i_) {                                           \
    const float* p_ = Axf + i_ * 8 * 384 + (KS) * 64;                        \
    SET[2 * i_]     = *(const float4*)p_;                                    \
    SET[2 * i_ + 1] = *(const float4*)(p_ + 4);                              \
  } } while (0)

#define AWRITE(SET, SEL) do {                                                \
  _Pragma("unroll")                                                          \
  for (int i_ = 0; i_ < 4; ++i_) {                                           \
    s16x8 pk_;                                                               \
    pk_[0] = f2bf(SET[2*i_].x);   pk_[1] = f2bf(SET[2*i_].y);                \
    pk_[2] = f2bf(SET[2*i_].z);   pk_[3] = f2bf(SET[2*i_].w);                \
    pk_[4] = f2bf(SET[2*i_+1].x); pk_[5] = f2bf(SET[2*i_+1].y);              \
    pk_[6] = f2bf(SET[2*i_+1].z); pk_[7] = f2bf(SET[2*i_+1].w);              \
    *(s16x8*)(lds + (SEL) * 8192 + adst + i_ * 512) = pk_;                   \
  } } while (0)

#define STAGE_B(KS, SEL) do {                                                \
  _Pragma("unroll")                                                          \
  for (int j_ = 0; j_ < 6; ++j_)                                             \
    gload_lds16(BbT[j_] + (KS) * 64,                                         \
                lds + 16384 + (SEL) * 12288 + (wv * 6 + j_) * 512);          \
  } while (0)

#define COMPUTE(SEL) do {                                                    \
  const short* Acur_ = lds + (SEL) * 8192;                                   \
  const short* Bcur_ = lds + 16384 + (SEL) * 12288;                          \
  _Pragma("unroll")                                                          \
  for (int kk = 0; kk < 2; ++kk) {                                           \
    s16x8 af[4], bq[6];                                                      \
    _Pragma("unroll")                                                        \
    for (int f = 0; f < 4; ++f) {                                            \
      const int arow = wm * 64 + f * 16 + lr;                                \
      const int ac = (kk * 4 + lg) ^ (arow & 7);                             \
      af[f] = *(const s16x8*)(Acur_ + arow * 64 + ac * 8);                   \
    }                                                                        \
    _Pragma("unroll")                                                        \
    for (int fn = 0; fn < 6; ++fn) {                                         \
      const int brow = wn * 96 + fn * 16 + lr;                               \
      const int bc = (kk * 4 + lg) ^ (brow & 7);                             \
      bq[fn] = *(const s16x8*)(Bcur_ + brow * 64 + bc * 8);                  \
    }                                                                        \
    _Pragma("unroll")                                                        \
    for (int fn = 0; fn < 6; ++fn)                                           \
      _Pragma("unroll")                                                      \
      for (int fm = 0; fm < 4; ++fm)                                         \
        acc[fn][fm] = MFMA16(bq[fn], af[fm], acc[fn][fm]);   /* W·X^T */     \
  } } while (0)

#define ITER(T, ACUR, ANXT, WTOP) do {                                       \
  asm volatile("s_waitcnt vmcnt(" #WTOP ")" ::: "memory");                   \
  __builtin_amdgcn_s_barrier();                                              \
  COMPUTE((T) & 1);                                                          \
  asm volatile("s_waitcnt lgkmcnt(0)" ::: "memory");  /* WAR drain */        \
  __builtin_amdgcn_s_barrier();                                              \
  if ((T) + 2 < 6) {                                                         \
    STAGE_B((T) + 2, (T) & 1);                                               \
    asm volatile("s_waitcnt vmcnt(6)" ::: "memory");  /* A(T+2) landed */    \
    AWRITE(ACUR, (T) & 1);                                                   \
    if ((T) + 3 < 6) ALOAD(ANXT, (T) + 3);                                   \
    asm volatile("s_waitcnt lgkmcnt(0)" ::: "memory"); /* writes drained */  \
  } } while (0)

  // prologue: A0,A1 (16 vm) + B0,B1 (12 vm)
  ALOAD(a0, 0);
  ALOAD(a1, 1);
  STAGE_B(0, 0);
  STAGE_B(1, 1);
  asm volatile("s_waitcnt vmcnt(20)" ::: "memory");   // a0 landed
  AWRITE(a0, 0);
  asm volatile("s_waitcnt vmcnt(12)" ::: "memory");   // a1 landed
  AWRITE(a1, 1);
  ALOAD(a0, 2);                                       // A for iter 2, early
  asm volatile("s_waitcnt lgkmcnt(0)" ::: "memory");  // our ds_writes done

  ITER(0, a0, a1, 14);
  ITER(1, a1, a0, 14);
  ITER(2, a0, a1, 14);
  ITER(3, a1, a0, 14);
  ITER(4, a0, a1, 6);
  ITER(5, a1, a0, 0);
#undef ITER
#undef COMPUTE
#undef STAGE_B
#undef AWRITE
#undef ALOAD

  // final ITER's lgkm(0)+barrier drained all GEMM LDS reads block-wide;
  // per-wave attn scratch below may overwrite the staging region.

  // ---- attention, one (window, head) per wave; Q/K stay in registers ----
  const int w = mt * 2 + wm, h = hg * 2 + wn;
  short* Vts = lds + wv * 4992;          // [32][76] V^T (stride 76: no 4-way)
  short* Os  = Vts + 2432;               // [64][40] epilogue staging

  // V scatter: Vts[d][tok], d = fv*16+lg*4+r, tok = fm*16+lr
#pragma unroll
  for (int fv = 0; fv < 2; ++fv)
#pragma unroll
    for (int fm = 0; fm < 4; ++fm)
#pragma unroll
      for (int r = 0; r < 4; ++r)
        Vts[(fv * 16 + lg * 4 + r) * 76 + fm * 16 + lr] =
            f2bf(acc[4 + fv][fm][r]);

  // pack K (A-op: lane=row kt) and Q (B-op: lane=col q) frags in-register;
  // slot j -> d = 16*(j>>2) + 4*lg + (j&3)  (same sigma on both operands)
  s16x8 ka[4], qb[4];
#pragma unroll
  for (int f = 0; f < 4; ++f) {
    s16x8 tk, tq;
#pragma unroll
    for (int j = 0; j < 8; ++j) {
      tk[j] = f2bf(acc[2 + (j >> 2)][f][j & 3]);
      tq[j] = f2bf(acc[0 + (j >> 2)][f][j & 3]);
    }
    ka[f] = tk; qb[f] = tq;
  }

  // S^T = K·Q^T  (rows kt, cols q), K-dim 32
  f32x4 st[4][4];
#pragma unroll
  for (int fk = 0; fk < 4; ++fk)
#pragma unroll
    for (int fq = 0; fq < 4; ++fq)
      st[fk][fq] = MFMA16(ka[fk], qb[fq], (f32x4)0.0f);

  // scale + bias + softmax over kt (per q column, per-lane + shfl 16/32)
  const float* bh = biasF + h * 4096;
#pragma unroll
  for (int fq = 0; fq < 4; ++fq) {
    const int q = fq * 16 + lr;
    float4 bv[4];
#pragma unroll
    for (int fk = 0; fk < 4; ++fk)
      bv[fk] = *(const float4*)(bh + q * 64 + fk * 16 + lg * 4);
    float mx = -3.0e38f;
#pragma unroll
    for (int fk = 0; fk < 4; ++fk)
#pragma unroll
      for (int r = 0; r < 4; ++r) {
        float v = st[fk][fq][r] * 0.17677669529663687f + ((const float*)&bv[fk])[r];
        st[fk][fq][r] = v;
        mx = fmaxf(mx, v);
      }
    mx = fmaxf(mx, __shfl_xor(mx, 16));
    mx = fmaxf(mx, __shfl_xor(mx, 32));
    float sm = 0.0f;
#pragma unroll
    for (int fk = 0; fk < 4; ++fk)
#pragma unroll
      for (int r = 0; r < 4; ++r) {
        float e = __expf(st[fk][fq][r] - mx);
        st[fk][fq][r] = e;
        sm += e;
      }
    sm += __shfl_xor(sm, 16);
    sm += __shfl_xor(sm, 32);
    const float inv = 1.0f / sm;
#pragma unroll
    for (int fk = 0; fk < 4; ++fk)
#pragma unroll
      for (int r = 0; r < 4; ++r) st[fk][fq][r] *= inv;
  }

  // O^T = V^T · P^T ; sigma(g,j)=32kb+16(j>>2)+4g+(j&3) on both operands
  s16x8 va[2][2];
#pragma unroll
  for (int fd = 0; fd < 2; ++fd)
#pragma unroll
    for (int kb = 0; kb < 2; ++kb) {
      short4 v0 = *(const short4*)(Vts + (fd * 16 + lr) * 76 + kb * 32 + lg * 4);
      short4 v1 = *(const short4*)(Vts + (fd * 16 + lr) * 76 + kb * 32 + 16 + lg * 4);
      s16x8 tv;
      tv[0] = v0.x; tv[1] = v0.y; tv[2] = v0.z; tv[3] = v0.w;
      tv[4] = v1.x; tv[5] = v1.y; tv[6] = v1.z; tv[7] = v1.w;
      va[fd][kb] = tv;
    }
  f32x4 ot[2][4];
#pragma unroll
  for (int fd = 0; fd < 2; ++fd)
#pragma unroll
    for (int fq = 0; fq < 4; ++fq) ot[fd][fq] = (f32x4)0.0f;
#pragma unroll
  for (int kb = 0; kb < 2; ++kb)
#pragma unroll
    for (int fq = 0; fq < 4; ++fq) {
      s16x8 pb;
#pragma unroll
      for (int j = 0; j < 8; ++j)
        pb[j] = f2bf(st[2 * kb + (j >> 2)][fq][j & 3]);   // lane-local repack
#pragma unroll
      for (int fd = 0; fd < 2; ++fd)
        ot[fd][fq] = MFMA16(va[fd][kb], pb, ot[fd][fq]);
    }

  // epilogue: stage O [q][d] in Os, write coalesced 64B rows
#pragma unroll
  for (int fd = 0; fd < 2; ++fd)
#pragma unroll
    for (int fq = 0; fq < 4; ++fq)
#pragma unroll
      for (int r = 0; r < 4; ++r)
        Os[(fq * 16 + lr) * 40 + fd * 16 + lg * 4 + r] = f2bf(ot[fd][fq][r]);
  short* dst = AO + ((size_t)w * 64 + l) * 384 + h * 32;
  int4 o0 = *(const int4*)(Os + l * 40);
  int4 o1 = *(const int4*)(Os + l * 40 + 8);
  int4 o2 = *(const int4*)(Os + l * 40 + 16);
  int4 o3 = *(const int4*)(Os + l * 40 + 24);
  *(int4*)(dst)      = o0;
  *(int4*)(dst + 8)  = o1;
  *(int4*)(dst + 16) = o2;
  *(int4*)(dst + 24) = o3;
}

// ---------------- output projection: out = AO(bf16) @ Wo + bo, f32 out --------
// R7-proven BK=64 2-deep counted-vmcnt pipeline.
__global__ __launch_bounds__(256) void proj_kernel(
    const short* __restrict__ AO, const short* __restrict__ WoT,
    const float* __restrict__ bo, float* __restrict__ out)
{
  __shared__ short lds[32768];
  const int bid = blockIdx.x;
  const int wg = (bid & 7) * 294 + (bid >> 3);   // XCD swizzle (2352 = 8*294)
  const int nt = wg % 3, mt = wg / 3;
  const int t = threadIdx.x;
  const int wv = t >> 6, l = t & 63, lr = l & 15, lg = l >> 4;
  const int wm = wv >> 1, wn = wv & 1;

  f32x4 acc[4][4];
#pragma unroll
  for (int fm = 0; fm < 4; ++fm)
#pragma unroll
    for (int fn = 0; fn < 4; ++fn) acc[fm][fn] = (f32x4)0.0f;

  const int srow = wv * 32 + (l >> 3);
  const int cg = (l & 7) ^ (srow & 7);
  const short* Ab = AO  + (size_t)(mt * 128 + srow) * 384 + cg * 8;
  const short* Bb = WoT + (size_t)(nt * 128 + srow) * 384 + cg * 8;

#define STAGE(KS, SEL) do {                                                  \
  _Pragma("unroll")                                                          \
  for (int i_ = 0; i_ < 4; ++i_) {                                           \
    gload_lds16(Ab + i_ * 3072 + (KS) * 64,                                  \
                lds + (SEL) * 16384 + (wv * 4 + i_) * 512);                  \
    gload_lds16(Bb + i_ * 3072 + (KS) * 64,                                  \
                lds + (SEL) * 16384 + 8192 + (wv * 4 + i_) * 512);           \
  } } while (0)

#define COMPUTE(SEL) do {                                                    \
  const short* Acur_ = lds + (SEL) * 16384;                                  \
  const short* Bcur_ = Acur_ + 8192;                                         \
  _Pragma("unroll")                                                          \
  for (int kk = 0; kk < 2; ++kk) {                                           \
    s16x8 af[4], bf[4];                                                      \
    _Pragma("unroll")                                                        \
    for (int f = 0; f < 4; ++f) {                                            \
      const int arow = wm * 64 + f * 16 + lr;                                \
      const int ac = (kk * 4 + lg) ^ (arow & 7);                             \
      af[f] = *(const s16x8*)(Acur_ + arow * 64 + ac * 8);                   \
      const int brow = wn * 64 + f * 16 + lr;                                \
      const int bc = (kk * 4 + lg) ^ (brow & 7);                             \
      bf[f] = *(const s16x8*)(Bcur_ + brow * 64 + bc * 8);                   \
    }                                                                        \
    _Pragma("unroll")                                                        \
    for (int fm = 0; fm < 4; ++fm)                                           \
      _Pragma("unroll")                                                      \
      for (int fn = 0; fn < 4; ++fn)                                         \
        acc[fm][fn] = MFMA16(af[fm], bf[fn], acc[fm][fn]);                   \
  } } while (0)

#define ITER(T, WN) do {                                                     \
  asm volatile("s_waitcnt vmcnt(" #WN ")" ::: "memory");                     \
  __builtin_amdgcn_s_barrier();                                              \
  COMPUTE((T) & 1);                                                          \
  asm volatile("s_waitcnt lgkmcnt(0)" ::: "memory");  /* WAR drain */        \
  __builtin_amdgcn_s_barrier();                                              \
  if ((T) + 2 < 6) STAGE((T) + 2, (T) & 1);                                  \
  } while (0)

  STAGE(0, 0);
  STAGE(1, 1);
  ITER(0, 8); ITER(1, 8); ITER(2, 8); ITER(3, 8); ITER(4, 8); ITER(5, 0);
#undef ITER
#undef COMPUTE
#undef STAGE

#pragma unroll
  for (int fn = 0; fn < 4; ++fn) {
    const int n = nt * 128 + wn * 64 + fn * 16 + lr;
    const float bias = bo[n];
#pragma unroll
    for (int fm = 0; fm < 4; ++fm) {
      const int m0 = mt * 128 + wm * 64 + fm * 16 + lg * 4;
#pragma unroll
      for (int r = 0; r < 4; ++r)
        out[(size_t)(m0 + r) * 384 + n] = acc[fm][fn][r] + bias;
    }
  }
}

extern "C" void kernel_launch(void* const* d_in, const int* in_sizes, int n_in,
                              void* d_out, int out_size, void* d_ws, size_t ws_size,
                              hipStream_t stream)
{
  const float* X    = (const float*)d_in[0];
  const float* Wqkv = (const float*)d_in[1];
  const float* posb = (const float*)d_in[2];
  const float* Wo   = (const float*)d_in[3];
  const float* bo   = (const float*)d_in[4];
  const int*   relp = (const int*)d_in[5];
  float* out = (float*)d_out;

  // workspace carve — ~78.5 MB (Xbf eliminated)
  char* ws = (char*)d_ws;
  short* WqkvT = (short*)(ws);                 //   884,736 B
  short* WoT   = (short*)(ws + 884736);        //   294,912 B
  float* biasF = (float*)(ws + 1179648);       //   196,608 B
  short* AO    = (short*)(ws + 1376256);       // 77,070,336 B [100352][384]

  prep_kernel<<<2496, 256, 0, stream>>>(Wqkv, Wo, posb, relp, WqkvT, WoT, biasF);
  qkv_attn<<<4704, 256, 0, stream>>>(X, WqkvT, biasF, AO);
  proj_kernel<<<2352, 256, 0, stream>>>(AO, WoT, bo, out);
}